// Round 1
// baseline (2004.755 us; speedup 1.0000x reference)
//
#include <hip/hip_runtime.h>
#include <stdint.h>

// ============================================================================
// PopularNicheGraphBuilder: segment-sums -> normalize -> per-row db3 DWT stats
// (in LDS) -> exact replication of jax.random.beta (threefry + Marsaglia-Tsang
// log-space gamma).
//
// PARTITIONABLE=1 replicates jax_threefry_partitionable=True (modern default).
// Flip to 0 for the legacy threefry split/draw scheme.
// ============================================================================
#define PARTITIONABLE 1

typedef unsigned long long ull;

#define NUM_U 16384
#define NUM_I 8192
#define CAP_U 160
#define CAP_I 256

// output layout
#define OFF_UPW 0
#define OFF_UMW 16384
#define OFF_IPW 32768
#define OFF_IMW 40960
#define OFF_ACT 49152
#define OFF_POP 65536

// ---------------- threefry2x32 ----------------
struct K2 { uint32_t a, b; };

__host__ __device__ inline void tf2x32(uint32_t k0, uint32_t k1, uint32_t& x0, uint32_t& x1) {
  const uint32_t ks2 = k0 ^ k1 ^ 0x1BD11BDAu;
  x0 += k0; x1 += k1;
#define TF_R(r) { x0 += x1; x1 = (x1 << (r)) | (x1 >> (32 - (r))); x1 ^= x0; }
  TF_R(13) TF_R(15) TF_R(26) TF_R(6)
  x0 += k1; x1 += ks2 + 1u;
  TF_R(17) TF_R(29) TF_R(16) TF_R(24)
  x0 += ks2; x1 += k0 + 2u;
  TF_R(13) TF_R(15) TF_R(26) TF_R(6)
  x0 += k0; x1 += k1 + 3u;
  TF_R(17) TF_R(29) TF_R(16) TF_R(24)
  x0 += k1; x1 += ks2 + 4u;
  TF_R(13) TF_R(15) TF_R(26) TF_R(6)
  x0 += ks2; x1 += k0 + 5u;
#undef TF_R
}

__host__ __device__ inline K2 tf_enc(K2 k, uint32_t x0, uint32_t x1) {
  tf2x32(k.a, k.b, x0, x1);
  K2 r; r.a = x0; r.b = x1; return r;
}

// split(key) -> 2 children
__host__ __device__ inline void split2(K2 k, K2& c0, K2& c1) {
#if PARTITIONABLE
  c0 = tf_enc(k, 0u, 0u);
  c1 = tf_enc(k, 0u, 1u);
#else
  K2 p = tf_enc(k, 0u, 2u);
  K2 q = tf_enc(k, 1u, 3u);
  c0.a = p.a; c0.b = q.a;
  c1.a = p.b; c1.b = q.b;
#endif
}

// split(key, 3)
__device__ inline void split3(K2 k, K2& c0, K2& c1, K2& c2) {
#if PARTITIONABLE
  c0 = tf_enc(k, 0u, 0u);
  c1 = tf_enc(k, 0u, 1u);
  c2 = tf_enc(k, 0u, 2u);
#else
  K2 p = tf_enc(k, 0u, 3u);
  K2 q = tf_enc(k, 1u, 4u);
  K2 r = tf_enc(k, 2u, 5u);
  c0.a = p.a; c0.b = q.a;
  c1.a = r.a; c1.b = p.b;
  c2.a = q.b; c2.b = r.b;
#endif
}

// scalar random_bits(key, 32, ())
__device__ inline uint32_t draw_bits(K2 k) {
  K2 e = tf_enc(k, 0u, 0u);
#if PARTITIONABLE
  return e.a ^ e.b;
#else
  return e.a;
#endif
}

// split(key, B)[i]
__device__ inline K2 elem_key(K2 k, uint32_t i, uint32_t B) {
#if PARTITIONABLE
  return tf_enc(k, 0u, i);
#else
  if (i < (B >> 1)) {
    K2 p = tf_enc(k, 2u * i, B + 2u * i);
    K2 q = tf_enc(k, 2u * i + 1u, B + 2u * i + 1u);
    K2 r; r.a = p.a; r.b = q.a; return r;
  } else {
    uint32_t j = 2u * i - B;
    K2 p = tf_enc(k, j, 2u * i);
    K2 q = tf_enc(k, j + 1u, 2u * i + 1u);
    K2 r; r.a = p.b; r.b = q.b; return r;
  }
#endif
}

__device__ inline float u01_bits(uint32_t b) {
  return __uint_as_float((b >> 9) | 0x3F800000u) - 1.0f;
}

// XLA ErfInv32 (Giles polynomial) -- matches lax.erf_inv on f32
__device__ inline float erfinv_f32(float x) {
  float w = -log1pf(-x * x);
  float p;
  if (w < 5.0f) {
    w = w - 2.5f;
    p = 2.81022636e-08f;
    p = fmaf(p, w, 3.43273939e-07f);
    p = fmaf(p, w, -3.5233877e-06f);
    p = fmaf(p, w, -4.39150654e-06f);
    p = fmaf(p, w, 0.00021858087f);
    p = fmaf(p, w, -0.00125372503f);
    p = fmaf(p, w, -0.00417768164f);
    p = fmaf(p, w, 0.246640727f);
    p = fmaf(p, w, 1.50140941f);
  } else {
    w = sqrtf(w) - 3.0f;
    p = -0.000200214257f;
    p = fmaf(p, w, 0.000100950558f);
    p = fmaf(p, w, 0.00134934322f);
    p = fmaf(p, w, -0.00367342844f);
    p = fmaf(p, w, 0.00573950773f);
    p = fmaf(p, w, -0.0076224613f);
    p = fmaf(p, w, 0.00943887047f);
    p = fmaf(p, w, 1.00167406f);
    p = fmaf(p, w, 2.83297682f);
  }
  return p * x;
}

// jax _gamma_one with log_space=True (Marsaglia-Tsang + boost)
__device__ float log_gamma_sample(K2 key, float alpha_orig) {
  const bool boost = (alpha_orig >= 1.0f);
  const float alpha = boost ? alpha_orig : (alpha_orig + 1.0f);
  const float d = alpha - 0.33333334f;
  const float c = 0.33333334f / sqrtf(d);

  K2 k0, sub;
  split2(key, k0, sub);
  const float u_boost = u01_bits(draw_bits(sub));

  K2 kcur = k0;
  float X = 0.0f, V = 1.0f, U = 2.0f;
  while ((U >= 1.0f - 0.0331f * (X * X)) &&
         (logf(U) >= X * 0.5f + d * ((1.0f - V) + logf(V)))) {
    K2 knext, xk, Uk;
    split3(kcur, knext, xk, Uk);
    kcur = knext;
    float x, v;
    K2 ik = xk;
    do {
      K2 in0, isub;
      split2(ik, in0, isub);
      ik = in0;
      float f = u01_bits(draw_bits(isub));
      // uniform(lo=nextafter(-1,0), hi=1): (hi-lo) rounds to exactly 2.0f
      float u = fmaxf(-0.99999994f, f * 2.0f + (-0.99999994f));
      x = 1.41421356f * erfinv_f32(u);   // sqrt(2) as f32
      v = 1.0f + x * c;
    } while (v <= 0.0f);
    X = x * x;
    V = (v * v) * v;
    U = u01_bits(draw_bits(Uk));
  }
  float lg = logf(d * V);
  if (!boost) lg += log1pf(-u_boost) / alpha_orig;
  return lg;
}

// ---------------- pipeline kernels ----------------

__global__ __launch_bounds__(256) void zero_kernel(ull* p, int n) {
  int i = blockIdx.x * 256 + threadIdx.x;
  if (i < n) p[i] = 0ull;
}

__global__ __launch_bounds__(256) void count_kernel(const int* __restrict__ item,
                                                    const float* __restrict__ val, int n,
                                                    int* __restrict__ cnt, ull* __restrict__ sv) {
  for (int k = blockIdx.x * 256 + threadIdx.x; k < n; k += gridDim.x * 256) {
    int it = item[k];
    atomicAdd(&cnt[it], 1);
    atomicAdd(&sv[it], (ull)llrintf(val[k] * 4294967296.0f));  // fixed-point 2^32
  }
}

__global__ __launch_bounds__(256) void pop_raw_kernel(const int* __restrict__ cnt,
                                                      const ull* __restrict__ sv,
                                                      float* __restrict__ pop,
                                                      double* __restrict__ nrm2) {
  __shared__ float red[4];
  int i = blockIdx.x * 256 + threadIdx.x;
  float p = 0.0f;
  if (i < NUM_I) {
    float svf = (float)((double)sv[i] * (1.0 / 4294967296.0));
    p = svf * log1pf((float)cnt[i]);
    pop[i] = p;
  }
  float sq = p * p;
  for (int o = 32; o > 0; o >>= 1) sq += __shfl_down(sq, o);
  if ((threadIdx.x & 63) == 0) red[threadIdx.x >> 6] = sq;
  __syncthreads();
  if (threadIdx.x == 0) atomicAdd(nrm2, (double)(red[0] + red[1] + red[2] + red[3]));
}

__global__ __launch_bounds__(256) void pop_norm_kernel(float* __restrict__ pop,
                                                       const double* __restrict__ nrm2,
                                                       float* __restrict__ out) {
  int i = blockIdx.x * 256 + threadIdx.x;
  if (i < NUM_I) {
    float nrm = sqrtf((float)(*nrm2));
    float v = pop[i] / (nrm + 1e-8f);
    pop[i] = v;
    out[OFF_POP + i] = v;
  }
}

__global__ __launch_bounds__(256) void act_accum_kernel(const int* __restrict__ user,
                                                        const int* __restrict__ item,
                                                        const float* __restrict__ val, int n,
                                                        const float* __restrict__ pop,
                                                        ull* __restrict__ acc) {
  for (int k = blockIdx.x * 256 + threadIdx.x; k < n; k += gridDim.x * 256) {
    float term = val[k] / log1pf(pop[item[k]] + 1e-8f);
    atomicAdd(&acc[user[k]], (ull)llrintf(term * 16777216.0f));  // fixed-point 2^24
  }
}

__global__ __launch_bounds__(256) void act_pre_kernel(const ull* __restrict__ acc,
                                                      float* __restrict__ act,
                                                      double* __restrict__ nrm2) {
  __shared__ float red[4];
  int u = blockIdx.x * 256 + threadIdx.x;
  float a = 0.0f;
  if (u < NUM_U) {
    a = (float)((double)acc[u] * (1.0 / 16777216.0));
    act[u] = a;
  }
  float sq = a * a;
  for (int o = 32; o > 0; o >>= 1) sq += __shfl_down(sq, o);
  if ((threadIdx.x & 63) == 0) red[threadIdx.x >> 6] = sq;
  __syncthreads();
  if (threadIdx.x == 0) atomicAdd(nrm2, (double)(red[0] + red[1] + red[2] + red[3]));
}

__global__ __launch_bounds__(256) void act_norm_kernel(float* __restrict__ act,
                                                       const double* __restrict__ nrm2,
                                                       float* __restrict__ out) {
  int u = blockIdx.x * 256 + threadIdx.x;
  if (u < NUM_U) {
    float nrm = sqrtf((float)(*nrm2));
    float v = act[u] / (nrm + 1e-8f);
    act[u] = v;
    out[OFF_ACT + u] = v;
  }
}

__global__ __launch_bounds__(256) void fill_kernel(const int* __restrict__ user,
                                                   const int* __restrict__ item, int n,
                                                   int* __restrict__ fu, int* __restrict__ fi,
                                                   uint32_t* __restrict__ lu, uint32_t* __restrict__ li) {
  for (int k = blockIdx.x * 256 + threadIdx.x; k < n; k += gridDim.x * 256) {
    int u = user[k];
    int p = atomicAdd(&fu[u], 1);
    if (p < CAP_U) lu[(size_t)u * CAP_U + p] = (uint32_t)k;
    int it = item[k];
    int q = atomicAdd(&fi[it], 1);
    if (q < CAP_I) li[(size_t)it * CAP_I + q] = (uint32_t)k;
  }
}

// per-row 3-level db3 DWT stats, dense row built in LDS, last-write-wins dedup
template <int N, int M1, int M2, int M3, int CAP>
__global__ __launch_bounds__(256) void dwt_rows_kernel(
    const uint32_t* __restrict__ klist, const int* __restrict__ rowlen,
    const int* __restrict__ colsrc, const float* __restrict__ values,
    const float* __restrict__ scale_vec,
    float* __restrict__ low_out, float* __restrict__ high_out) {
  extern __shared__ float smem[];
  float* x = smem;                 // N
  float* lo1 = x + N;              // M1
  float* lo2 = lo1 + M1;           // M2
  float* ev = lo2 + M2;            // CAP
  int* ecol = (int*)(ev + CAP);    // CAP
  int* ek = (int*)(ecol + CAP);    // CAP
  float* red = (float*)(ek + CAP); // 16

  const int r = blockIdx.x;
  const int tid = threadIdx.x;
  const float scale = 1.0f + scale_vec[r];
  int n = rowlen[r];
  if (n > CAP) n = CAP;

  for (int i = tid; i < N; i += 256) x[i] = 0.0f;
  for (int e = tid; e < n; e += 256) {
    uint32_t k = klist[(size_t)r * CAP + e];
    ecol[e] = colsrc[k];
    ek[e] = (int)k;
    ev[e] = values[k] * scale;
  }
  __syncthreads();
  // duplicate resolution: entry with max original index wins (XLA CPU scatter)
  for (int e = tid; e < n; e += 256) {
    int cme = ecol[e], kme = ek[e];
    bool win = true;
    for (int j = 0; j < n; ++j)
      if (ecol[j] == cme && ek[j] > kme) { win = false; break; }
    if (win) x[cme] = ev[e];
  }
  __syncthreads();

  const float HL[6] = {0.035226291882100656f, -0.08544127388224149f, -0.13501102001039084f,
                       0.4598775021193313f, 0.8068915093133388f, 0.3326705529509569f};
  const float HH[6] = {-0.3326705529509569f, 0.8068915093133388f, -0.4598775021193313f,
                       -0.13501102001039084f, 0.08544127388224149f, 0.035226291882100656f};

  float h1 = 0.0f, h2 = 0.0f, h3 = 0.0f, slo = 0.0f;
  // level 1: x[N] -> lo1[M1], y[m] = sum_t h[t]*x[2m+1-t]
  for (int m = tid; m < M1; m += 256) {
    float lo = 0.0f, hi = 0.0f;
    int base = 2 * m + 1;
#pragma unroll
    for (int t = 0; t < 6; ++t) {
      int idx = base - t;
      if (idx >= 0 && idx < N) {
        float xv = x[idx];
        lo += HL[t] * xv;
        hi += HH[t] * xv;
      }
    }
    lo1[m] = lo;
    h1 += hi * hi;
  }
  __syncthreads();
  // level 2: lo1[M1] -> lo2[M2]
  for (int m = tid; m < M2; m += 256) {
    float lo = 0.0f, hi = 0.0f;
    int base = 2 * m + 1;
#pragma unroll
    for (int t = 0; t < 6; ++t) {
      int idx = base - t;
      if (idx >= 0 && idx < M1) {
        float xv = lo1[idx];
        lo += HL[t] * xv;
        hi += HH[t] * xv;
      }
    }
    lo2[m] = lo;
    h2 += hi * hi;
  }
  __syncthreads();
  // level 3: lo2[M2] -> (sum of lo3, hi3 norm2)
  for (int m = tid; m < M3; m += 256) {
    float lo = 0.0f, hi = 0.0f;
    int base = 2 * m + 1;
#pragma unroll
    for (int t = 0; t < 6; ++t) {
      int idx = base - t;
      if (idx >= 0 && idx < M2) {
        float xv = lo2[idx];
        lo += HL[t] * xv;
        hi += HH[t] * xv;
      }
    }
    slo += lo;
    h3 += hi * hi;
  }

  for (int o = 32; o > 0; o >>= 1) {
    h1 += __shfl_down(h1, o);
    h2 += __shfl_down(h2, o);
    h3 += __shfl_down(h3, o);
    slo += __shfl_down(slo, o);
  }
  int w = tid >> 6, lane = tid & 63;
  if (lane == 0) { red[w] = h1; red[4 + w] = h2; red[8 + w] = h3; red[12 + w] = slo; }
  __syncthreads();
  if (tid == 0) {
    float s1 = red[0] + red[1] + red[2] + red[3];
    float s2 = red[4] + red[5] + red[6] + red[7];
    float s3 = red[8] + red[9] + red[10] + red[11];
    float sl = red[12] + red[13] + red[14] + red[15];
    low_out[r] = sl / (float)M3;
    high_out[r] = sqrtf(s1) + sqrtf(s2) + sqrtf(s3);
  }
}

__global__ __launch_bounds__(256) void beta_kernel(
    const float* __restrict__ u_low, const float* __restrict__ u_high,
    const float* __restrict__ i_low, const float* __restrict__ i_high,
    float* __restrict__ out, K2 kAu, K2 kBu, K2 kAi, K2 kBi) {
  int t = blockIdx.x * 256 + threadIdx.x;
  if (t >= NUM_U + NUM_I) return;
  float low, high;
  K2 ka, kb;
  int o0, o1;
  if (t < NUM_U) {
    low = u_low[t]; high = u_high[t];
    ka = elem_key(kAu, (uint32_t)t, (uint32_t)NUM_U);
    kb = elem_key(kBu, (uint32_t)t, (uint32_t)NUM_U);
    o0 = OFF_UPW + t; o1 = OFF_UMW + t;
  } else {
    int j = t - NUM_U;
    low = i_low[j]; high = i_high[j];
    ka = elem_key(kAi, (uint32_t)j, (uint32_t)NUM_I);
    kb = elem_key(kBi, (uint32_t)j, (uint32_t)NUM_I);
    o0 = OFF_IPW + j; o1 = OFF_IMW + j;
  }
  float a1 = fmaxf(low, 1e-6f);
  float a2 = fmaxf(high, 1e-6f);
  float s = a1 + a2;
  a1 = a1 / s;
  a2 = a2 / s;
  float lga = log_gamma_sample(ka, 10.0f * a1);
  float lgb = log_gamma_sample(kb, 10.0f * a2);
  float m = fmaxf(lga, lgb);
  float na = expf(lga - m);
  float nb = expf(lgb - m);
  float w = na / (na + nb);
  out[o0] = w;
  out[o1] = 1.0f - w;
}

// ---------------- host ----------------
extern "C" void kernel_launch(void* const* d_in, const int* in_sizes, int n_in,
                              void* d_out, int out_size, void* d_ws, size_t ws_size,
                              hipStream_t stream) {
  const int* user_idx = (const int*)d_in[0];
  const int* item_idx = (const int*)d_in[1];
  const float* values = (const float*)d_in[2];
  const int NNZ = in_sizes[0];

  char* ws = (char*)d_ws;
  double* nrm2_pop = (double*)(ws + 0);
  double* nrm2_act = (double*)(ws + 8);
  ull* sv_acc = (ull*)(ws + 16);
  ull* act_acc = (ull*)(ws + 65552);
  int* cnt_i = (int*)(ws + 196624);
  float* pop = (float*)(ws + 229392);
  float* act = (float*)(ws + 262160);
  int* fill_u = (int*)(ws + 327696);
  int* fill_i = (int*)(ws + 393232);
  float* u_low = (float*)(ws + 426000);
  float* u_high = (float*)(ws + 491536);
  float* i_low = (float*)(ws + 557072);
  float* i_high = (float*)(ws + 589840);
  uint32_t* klist_u = (uint32_t*)(ws + 622608);
  uint32_t* klist_i = (uint32_t*)(ws + 11108368);
  float* out = (float*)d_out;

  // host-side key derivation: root=key(42)=(0,42); ku,ki=split(root); then
  // (key_a,key_b)=split(k) inside beta for each side.
  K2 root; root.a = 0u; root.b = 42u;
  K2 ku, ki, kAu, kBu, kAi, kBi;
  split2(root, ku, ki);
  split2(ku, kAu, kBu);
  split2(ki, kAi, kBi);

  const int zero_words = 622608 / 8;
  zero_kernel<<<(zero_words + 255) / 256, 256, 0, stream>>>((ull*)ws, zero_words);
  count_kernel<<<1024, 256, 0, stream>>>(item_idx, values, NNZ, cnt_i, sv_acc);
  pop_raw_kernel<<<NUM_I / 256, 256, 0, stream>>>(cnt_i, sv_acc, pop, nrm2_pop);
  pop_norm_kernel<<<NUM_I / 256, 256, 0, stream>>>(pop, nrm2_pop, out);
  act_accum_kernel<<<1024, 256, 0, stream>>>(user_idx, item_idx, values, NNZ, pop, act_acc);
  act_pre_kernel<<<NUM_U / 256, 256, 0, stream>>>(act_acc, act, nrm2_act);
  act_norm_kernel<<<NUM_U / 256, 256, 0, stream>>>(act, nrm2_act, out);
  fill_kernel<<<1024, 256, 0, stream>>>(user_idx, item_idx, NNZ, fill_u, fill_i, klist_u, klist_i);

  // user rows: N=8192, M1=4098, M2=2051, M3=1028
  constexpr int U_SHM = (8192 + 4098 + 2051 + CAP_U) * 4 + CAP_U * 8 + 16 * 4;
  // item rows: N=16384, M1=8194, M2=4099, M3=2052
  constexpr int I_SHM = (16384 + 8194 + 4099 + CAP_I) * 4 + CAP_I * 8 + 16 * 4;
  hipFuncSetAttribute((const void*)dwt_rows_kernel<8192, 4098, 2051, 1028, CAP_U>,
                      hipFuncAttributeMaxDynamicSharedMemorySize, U_SHM);
  hipFuncSetAttribute((const void*)dwt_rows_kernel<16384, 8194, 4099, 2052, CAP_I>,
                      hipFuncAttributeMaxDynamicSharedMemorySize, I_SHM);

  dwt_rows_kernel<8192, 4098, 2051, 1028, CAP_U><<<NUM_U, 256, U_SHM, stream>>>(
      klist_u, fill_u, item_idx, values, act, u_low, u_high);
  dwt_rows_kernel<16384, 8194, 4099, 2052, CAP_I><<<NUM_I, 256, I_SHM, stream>>>(
      klist_i, fill_i, user_idx, values, pop, i_low, i_high);

  beta_kernel<<<(NUM_U + NUM_I + 255) / 256, 256, 0, stream>>>(
      u_low, u_high, i_low, i_high, out, kAu, kBu, kAi, kBi);
}

// Round 2
// 1540.281 us; speedup vs baseline: 1.3016x; 1.3016x over previous
//
#include <hip/hip_runtime.h>
#include <stdint.h>

// ============================================================================
// PopularNicheGraphBuilder: segment-sums -> normalize -> per-row db3 DWT stats
// (in LDS) -> exact replication of jax.random.beta (threefry + Marsaglia-Tsang
// log-space gamma).
//
// Round 2: DWT kernels rewritten -- padded LDS buffers (no bounds checks in
// the 6-tap gathers) + 4-way position ILP with loads hoisted to registers.
// Per-thread accumulation order identical to round 1 (numerics preserved).
// ============================================================================
#define PARTITIONABLE 1

typedef unsigned long long ull;

#define NUM_U 16384
#define NUM_I 8192
#define CAP_U 160
#define CAP_I 256

// output layout
#define OFF_UPW 0
#define OFF_UMW 16384
#define OFF_IPW 32768
#define OFF_IMW 40960
#define OFF_ACT 49152
#define OFF_POP 65536

// ---------------- threefry2x32 ----------------
struct K2 { uint32_t a, b; };

__host__ __device__ inline void tf2x32(uint32_t k0, uint32_t k1, uint32_t& x0, uint32_t& x1) {
  const uint32_t ks2 = k0 ^ k1 ^ 0x1BD11BDAu;
  x0 += k0; x1 += k1;
#define TF_R(r) { x0 += x1; x1 = (x1 << (r)) | (x1 >> (32 - (r))); x1 ^= x0; }
  TF_R(13) TF_R(15) TF_R(26) TF_R(6)
  x0 += k1; x1 += ks2 + 1u;
  TF_R(17) TF_R(29) TF_R(16) TF_R(24)
  x0 += ks2; x1 += k0 + 2u;
  TF_R(13) TF_R(15) TF_R(26) TF_R(6)
  x0 += k0; x1 += k1 + 3u;
  TF_R(17) TF_R(29) TF_R(16) TF_R(24)
  x0 += k1; x1 += ks2 + 4u;
  TF_R(13) TF_R(15) TF_R(26) TF_R(6)
  x0 += ks2; x1 += k0 + 5u;
#undef TF_R
}

__host__ __device__ inline K2 tf_enc(K2 k, uint32_t x0, uint32_t x1) {
  tf2x32(k.a, k.b, x0, x1);
  K2 r; r.a = x0; r.b = x1; return r;
}

// split(key) -> 2 children
__host__ __device__ inline void split2(K2 k, K2& c0, K2& c1) {
#if PARTITIONABLE
  c0 = tf_enc(k, 0u, 0u);
  c1 = tf_enc(k, 0u, 1u);
#else
  K2 p = tf_enc(k, 0u, 2u);
  K2 q = tf_enc(k, 1u, 3u);
  c0.a = p.a; c0.b = q.a;
  c1.a = p.b; c1.b = q.b;
#endif
}

// split(key, 3)
__device__ inline void split3(K2 k, K2& c0, K2& c1, K2& c2) {
#if PARTITIONABLE
  c0 = tf_enc(k, 0u, 0u);
  c1 = tf_enc(k, 0u, 1u);
  c2 = tf_enc(k, 0u, 2u);
#else
  K2 p = tf_enc(k, 0u, 3u);
  K2 q = tf_enc(k, 1u, 4u);
  K2 r = tf_enc(k, 2u, 5u);
  c0.a = p.a; c0.b = q.a;
  c1.a = r.a; c1.b = p.b;
  c2.a = q.b; c2.b = r.b;
#endif
}

// scalar random_bits(key, 32, ())
__device__ inline uint32_t draw_bits(K2 k) {
  K2 e = tf_enc(k, 0u, 0u);
#if PARTITIONABLE
  return e.a ^ e.b;
#else
  return e.a;
#endif
}

// split(key, B)[i]
__device__ inline K2 elem_key(K2 k, uint32_t i, uint32_t B) {
#if PARTITIONABLE
  return tf_enc(k, 0u, i);
#else
  if (i < (B >> 1)) {
    K2 p = tf_enc(k, 2u * i, B + 2u * i);
    K2 q = tf_enc(k, 2u * i + 1u, B + 2u * i + 1u);
    K2 r; r.a = p.a; r.b = q.a; return r;
  } else {
    uint32_t j = 2u * i - B;
    K2 p = tf_enc(k, j, 2u * i);
    K2 q = tf_enc(k, j + 1u, 2u * i + 1u);
    K2 r; r.a = p.b; r.b = q.b; return r;
  }
#endif
}

__device__ inline float u01_bits(uint32_t b) {
  return __uint_as_float((b >> 9) | 0x3F800000u) - 1.0f;
}

// XLA ErfInv32 (Giles polynomial) -- matches lax.erf_inv on f32
__device__ inline float erfinv_f32(float x) {
  float w = -log1pf(-x * x);
  float p;
  if (w < 5.0f) {
    w = w - 2.5f;
    p = 2.81022636e-08f;
    p = fmaf(p, w, 3.43273939e-07f);
    p = fmaf(p, w, -3.5233877e-06f);
    p = fmaf(p, w, -4.39150654e-06f);
    p = fmaf(p, w, 0.00021858087f);
    p = fmaf(p, w, -0.00125372503f);
    p = fmaf(p, w, -0.00417768164f);
    p = fmaf(p, w, 0.246640727f);
    p = fmaf(p, w, 1.50140941f);
  } else {
    w = sqrtf(w) - 3.0f;
    p = -0.000200214257f;
    p = fmaf(p, w, 0.000100950558f);
    p = fmaf(p, w, 0.00134934322f);
    p = fmaf(p, w, -0.00367342844f);
    p = fmaf(p, w, 0.00573950773f);
    p = fmaf(p, w, -0.0076224613f);
    p = fmaf(p, w, 0.00943887047f);
    p = fmaf(p, w, 1.00167406f);
    p = fmaf(p, w, 2.83297682f);
  }
  return p * x;
}

// jax _gamma_one with log_space=True (Marsaglia-Tsang + boost)
__device__ float log_gamma_sample(K2 key, float alpha_orig) {
  const bool boost = (alpha_orig >= 1.0f);
  const float alpha = boost ? alpha_orig : (alpha_orig + 1.0f);
  const float d = alpha - 0.33333334f;
  const float c = 0.33333334f / sqrtf(d);

  K2 k0, sub;
  split2(key, k0, sub);
  const float u_boost = u01_bits(draw_bits(sub));

  K2 kcur = k0;
  float X = 0.0f, V = 1.0f, U = 2.0f;
  while ((U >= 1.0f - 0.0331f * (X * X)) &&
         (logf(U) >= X * 0.5f + d * ((1.0f - V) + logf(V)))) {
    K2 knext, xk, Uk;
    split3(kcur, knext, xk, Uk);
    kcur = knext;
    float x, v;
    K2 ik = xk;
    do {
      K2 in0, isub;
      split2(ik, in0, isub);
      ik = in0;
      float f = u01_bits(draw_bits(isub));
      // uniform(lo=nextafter(-1,0), hi=1): (hi-lo) rounds to exactly 2.0f
      float u = fmaxf(-0.99999994f, f * 2.0f + (-0.99999994f));
      x = 1.41421356f * erfinv_f32(u);   // sqrt(2) as f32
      v = 1.0f + x * c;
    } while (v <= 0.0f);
    X = x * x;
    V = (v * v) * v;
    U = u01_bits(draw_bits(Uk));
  }
  float lg = logf(d * V);
  if (!boost) lg += log1pf(-u_boost) / alpha_orig;
  return lg;
}

// ---------------- pipeline kernels ----------------

__global__ __launch_bounds__(256) void zero_kernel(ull* p, int n) {
  int i = blockIdx.x * 256 + threadIdx.x;
  if (i < n) p[i] = 0ull;
}

__global__ __launch_bounds__(256) void count_kernel(const int* __restrict__ item,
                                                    const float* __restrict__ val, int n,
                                                    int* __restrict__ cnt, ull* __restrict__ sv) {
  for (int k = blockIdx.x * 256 + threadIdx.x; k < n; k += gridDim.x * 256) {
    int it = item[k];
    atomicAdd(&cnt[it], 1);
    atomicAdd(&sv[it], (ull)llrintf(val[k] * 4294967296.0f));  // fixed-point 2^32
  }
}

__global__ __launch_bounds__(256) void pop_raw_kernel(const int* __restrict__ cnt,
                                                      const ull* __restrict__ sv,
                                                      float* __restrict__ pop,
                                                      double* __restrict__ nrm2) {
  __shared__ float red[4];
  int i = blockIdx.x * 256 + threadIdx.x;
  float p = 0.0f;
  if (i < NUM_I) {
    float svf = (float)((double)sv[i] * (1.0 / 4294967296.0));
    p = svf * log1pf((float)cnt[i]);
    pop[i] = p;
  }
  float sq = p * p;
  for (int o = 32; o > 0; o >>= 1) sq += __shfl_down(sq, o);
  if ((threadIdx.x & 63) == 0) red[threadIdx.x >> 6] = sq;
  __syncthreads();
  if (threadIdx.x == 0) atomicAdd(nrm2, (double)(red[0] + red[1] + red[2] + red[3]));
}

__global__ __launch_bounds__(256) void pop_norm_kernel(float* __restrict__ pop,
                                                       const double* __restrict__ nrm2,
                                                       float* __restrict__ out) {
  int i = blockIdx.x * 256 + threadIdx.x;
  if (i < NUM_I) {
    float nrm = sqrtf((float)(*nrm2));
    float v = pop[i] / (nrm + 1e-8f);
    pop[i] = v;
    out[OFF_POP + i] = v;
  }
}

__global__ __launch_bounds__(256) void act_accum_kernel(const int* __restrict__ user,
                                                        const int* __restrict__ item,
                                                        const float* __restrict__ val, int n,
                                                        const float* __restrict__ pop,
                                                        ull* __restrict__ acc) {
  for (int k = blockIdx.x * 256 + threadIdx.x; k < n; k += gridDim.x * 256) {
    float term = val[k] / log1pf(pop[item[k]] + 1e-8f);
    atomicAdd(&acc[user[k]], (ull)llrintf(term * 16777216.0f));  // fixed-point 2^24
  }
}

__global__ __launch_bounds__(256) void act_pre_kernel(const ull* __restrict__ acc,
                                                      float* __restrict__ act,
                                                      double* __restrict__ nrm2) {
  __shared__ float red[4];
  int u = blockIdx.x * 256 + threadIdx.x;
  float a = 0.0f;
  if (u < NUM_U) {
    a = (float)((double)acc[u] * (1.0 / 16777216.0));
    act[u] = a;
  }
  float sq = a * a;
  for (int o = 32; o > 0; o >>= 1) sq += __shfl_down(sq, o);
  if ((threadIdx.x & 63) == 0) red[threadIdx.x >> 6] = sq;
  __syncthreads();
  if (threadIdx.x == 0) atomicAdd(nrm2, (double)(red[0] + red[1] + red[2] + red[3]));
}

__global__ __launch_bounds__(256) void act_norm_kernel(float* __restrict__ act,
                                                       const double* __restrict__ nrm2,
                                                       float* __restrict__ out) {
  int u = blockIdx.x * 256 + threadIdx.x;
  if (u < NUM_U) {
    float nrm = sqrtf((float)(*nrm2));
    float v = act[u] / (nrm + 1e-8f);
    act[u] = v;
    out[OFF_ACT + u] = v;
  }
}

__global__ __launch_bounds__(256) void fill_kernel(const int* __restrict__ user,
                                                   const int* __restrict__ item, int n,
                                                   int* __restrict__ fu, int* __restrict__ fi,
                                                   uint32_t* __restrict__ lu, uint32_t* __restrict__ li) {
  for (int k = blockIdx.x * 256 + threadIdx.x; k < n; k += gridDim.x * 256) {
    int u = user[k];
    int p = atomicAdd(&fu[u], 1);
    if (p < CAP_U) lu[(size_t)u * CAP_U + p] = (uint32_t)k;
    int it = item[k];
    int q = atomicAdd(&fi[it], 1);
    if (q < CAP_I) li[(size_t)it * CAP_I + q] = (uint32_t)k;
  }
}

// One DWT analysis level over a padded LDS buffer.
// src/dst are PADDED buffers: data element i lives at buf[4+i]; front pad 4
// and back pad 8 are zero and never written. No bounds checks in the gather.
// Per-thread accumulation order identical to the round-1 kernel (m = tid,
// tid+256, tid+512, ...).
template <int MOUT, bool LAST>
__device__ inline void dwt_level_run(const float* __restrict__ src, float* __restrict__ dst,
                                     int tid, float& h_acc, float& lo_acc) {
  for (int m0 = tid; m0 < MOUT; m0 += 1024) {
    float lov[4], hiv[4];
    int mv[4]; bool okv[4];
#pragma unroll
    for (int u = 0; u < 4; ++u) {
      int m = m0 + (u << 8);
      bool ok = m < MOUT;
      mv[u] = m; okv[u] = ok;
      int mm = ok ? m : (MOUT - 1);
      const float* s = src + 2 * mm + 5;   // s[-t] == data[2*mm+1-t]
      float x0 = s[0], x1 = s[-1], x2 = s[-2], x3 = s[-3], x4 = s[-4], x5 = s[-5];
      float lo = 0.0f, hi = 0.0f;
      lo += 0.035226291882100656f * x0;  hi += -0.3326705529509569f * x0;
      lo += -0.08544127388224149f * x1;  hi += 0.8068915093133388f * x1;
      lo += -0.13501102001039084f * x2;  hi += -0.4598775021193313f * x2;
      lo += 0.4598775021193313f * x3;    hi += -0.13501102001039084f * x3;
      lo += 0.8068915093133388f * x4;    hi += 0.08544127388224149f * x4;
      lo += 0.3326705529509569f * x5;    hi += 0.035226291882100656f * x5;
      lov[u] = lo; hiv[u] = hi;
    }
#pragma unroll
    for (int u = 0; u < 4; ++u) {
      if (okv[u]) {
        if (!LAST) dst[4 + mv[u]] = lov[u];
        else lo_acc += lov[u];
        h_acc += hiv[u] * hiv[u];
      }
    }
  }
}

// per-row 3-level db3 DWT stats, dense row built in LDS, last-write-wins dedup
template <int N, int M1, int M2, int M3, int CAP>
__global__ __launch_bounds__(256) void dwt_rows_kernel(
    const uint32_t* __restrict__ klist, const int* __restrict__ rowlen,
    const int* __restrict__ colsrc, const float* __restrict__ values,
    const float* __restrict__ scale_vec,
    float* __restrict__ low_out, float* __restrict__ high_out) {
  extern __shared__ float smem[];
  float* xb = smem;                        // N + 12 (data at +4)
  float* lo1b = xb + (N + 12);             // M1 + 12
  float* lo2b = lo1b + (M1 + 12);          // M2 + 12
  float* ev = lo2b + (M2 + 12);            // CAP
  int* ecol = (int*)(ev + CAP);            // CAP
  int* ek = (int*)(ecol + CAP);            // CAP
  float* red = (float*)(ek + CAP);         // 16

  const int r = blockIdx.x;
  const int tid = threadIdx.x;
  const float scale = 1.0f + scale_vec[r];
  int n = rowlen[r];
  if (n > CAP) n = CAP;

  constexpr int TOT = (N + 12) + (M1 + 12) + (M2 + 12);
  for (int i = tid; i < TOT; i += 256) smem[i] = 0.0f;
  for (int e = tid; e < n; e += 256) {
    uint32_t k = klist[(size_t)r * CAP + e];
    ecol[e] = colsrc[k];
    ek[e] = (int)k;
    ev[e] = values[k] * scale;
  }
  __syncthreads();
  // duplicate resolution: entry with max original index wins (XLA CPU scatter)
  for (int e = tid; e < n; e += 256) {
    int cme = ecol[e], kme = ek[e];
    bool win = true;
    for (int j = 0; j < n; ++j)
      if (ecol[j] == cme && ek[j] > kme) { win = false; break; }
    if (win) xb[4 + cme] = ev[e];
  }
  __syncthreads();

  float h1 = 0.0f, h2 = 0.0f, h3 = 0.0f, slo = 0.0f;
  float dummy = 0.0f;
  dwt_level_run<M1, false>(xb, lo1b, tid, h1, dummy);
  __syncthreads();
  dwt_level_run<M2, false>(lo1b, lo2b, tid, h2, dummy);
  __syncthreads();
  dwt_level_run<M3, true>(lo2b, nullptr, tid, h3, slo);

  for (int o = 32; o > 0; o >>= 1) {
    h1 += __shfl_down(h1, o);
    h2 += __shfl_down(h2, o);
    h3 += __shfl_down(h3, o);
    slo += __shfl_down(slo, o);
  }
  int w = tid >> 6, lane = tid & 63;
  if (lane == 0) { red[w] = h1; red[4 + w] = h2; red[8 + w] = h3; red[12 + w] = slo; }
  __syncthreads();
  if (tid == 0) {
    float s1 = red[0] + red[1] + red[2] + red[3];
    float s2 = red[4] + red[5] + red[6] + red[7];
    float s3 = red[8] + red[9] + red[10] + red[11];
    float sl = red[12] + red[13] + red[14] + red[15];
    low_out[r] = sl / (float)M3;
    high_out[r] = sqrtf(s1) + sqrtf(s2) + sqrtf(s3);
  }
}

__global__ __launch_bounds__(256) void beta_kernel(
    const float* __restrict__ u_low, const float* __restrict__ u_high,
    const float* __restrict__ i_low, const float* __restrict__ i_high,
    float* __restrict__ out, K2 kAu, K2 kBu, K2 kAi, K2 kBi) {
  int t = blockIdx.x * 256 + threadIdx.x;
  if (t >= NUM_U + NUM_I) return;
  float low, high;
  K2 ka, kb;
  int o0, o1;
  if (t < NUM_U) {
    low = u_low[t]; high = u_high[t];
    ka = elem_key(kAu, (uint32_t)t, (uint32_t)NUM_U);
    kb = elem_key(kBu, (uint32_t)t, (uint32_t)NUM_U);
    o0 = OFF_UPW + t; o1 = OFF_UMW + t;
  } else {
    int j = t - NUM_U;
    low = i_low[j]; high = i_high[j];
    ka = elem_key(kAi, (uint32_t)j, (uint32_t)NUM_I);
    kb = elem_key(kBi, (uint32_t)j, (uint32_t)NUM_I);
    o0 = OFF_IPW + j; o1 = OFF_IMW + j;
  }
  float a1 = fmaxf(low, 1e-6f);
  float a2 = fmaxf(high, 1e-6f);
  float s = a1 + a2;
  a1 = a1 / s;
  a2 = a2 / s;
  float lga = log_gamma_sample(ka, 10.0f * a1);
  float lgb = log_gamma_sample(kb, 10.0f * a2);
  float m = fmaxf(lga, lgb);
  float na = expf(lga - m);
  float nb = expf(lgb - m);
  float w = na / (na + nb);
  out[o0] = w;
  out[o1] = 1.0f - w;
}

// ---------------- host ----------------
extern "C" void kernel_launch(void* const* d_in, const int* in_sizes, int n_in,
                              void* d_out, int out_size, void* d_ws, size_t ws_size,
                              hipStream_t stream) {
  const int* user_idx = (const int*)d_in[0];
  const int* item_idx = (const int*)d_in[1];
  const float* values = (const float*)d_in[2];
  const int NNZ = in_sizes[0];

  char* ws = (char*)d_ws;
  double* nrm2_pop = (double*)(ws + 0);
  double* nrm2_act = (double*)(ws + 8);
  ull* sv_acc = (ull*)(ws + 16);
  ull* act_acc = (ull*)(ws + 65552);
  int* cnt_i = (int*)(ws + 196624);
  float* pop = (float*)(ws + 229392);
  float* act = (float*)(ws + 262160);
  int* fill_u = (int*)(ws + 327696);
  int* fill_i = (int*)(ws + 393232);
  float* u_low = (float*)(ws + 426000);
  float* u_high = (float*)(ws + 491536);
  float* i_low = (float*)(ws + 557072);
  float* i_high = (float*)(ws + 589840);
  uint32_t* klist_u = (uint32_t*)(ws + 622608);
  uint32_t* klist_i = (uint32_t*)(ws + 11108368);
  float* out = (float*)d_out;

  // host-side key derivation: root=key(42)=(0,42); ku,ki=split(root); then
  // (key_a,key_b)=split(k) inside beta for each side.
  K2 root; root.a = 0u; root.b = 42u;
  K2 ku, ki, kAu, kBu, kAi, kBi;
  split2(root, ku, ki);
  split2(ku, kAu, kBu);
  split2(ki, kAi, kBi);

  const int zero_words = 622608 / 8;
  zero_kernel<<<(zero_words + 255) / 256, 256, 0, stream>>>((ull*)ws, zero_words);
  count_kernel<<<1024, 256, 0, stream>>>(item_idx, values, NNZ, cnt_i, sv_acc);
  pop_raw_kernel<<<NUM_I / 256, 256, 0, stream>>>(cnt_i, sv_acc, pop, nrm2_pop);
  pop_norm_kernel<<<NUM_I / 256, 256, 0, stream>>>(pop, nrm2_pop, out);
  act_accum_kernel<<<1024, 256, 0, stream>>>(user_idx, item_idx, values, NNZ, pop, act_acc);
  act_pre_kernel<<<NUM_U / 256, 256, 0, stream>>>(act_acc, act, nrm2_act);
  act_norm_kernel<<<NUM_U / 256, 256, 0, stream>>>(act, nrm2_act, out);
  fill_kernel<<<1024, 256, 0, stream>>>(user_idx, item_idx, NNZ, fill_u, fill_i, klist_u, klist_i);

  // user rows: N=8192, M1=4098, M2=2051, M3=1028
  constexpr int U_SHM = ((8192 + 12) + (4098 + 12) + (2051 + 12) + 3 * CAP_U + 16) * 4;
  // item rows: N=16384, M1=8194, M2=4099, M3=2052
  constexpr int I_SHM = ((16384 + 12) + (8194 + 12) + (4099 + 12) + 3 * CAP_I + 16) * 4;
  hipFuncSetAttribute((const void*)dwt_rows_kernel<8192, 4098, 2051, 1028, CAP_U>,
                      hipFuncAttributeMaxDynamicSharedMemorySize, U_SHM);
  hipFuncSetAttribute((const void*)dwt_rows_kernel<16384, 8194, 4099, 2052, CAP_I>,
                      hipFuncAttributeMaxDynamicSharedMemorySize, I_SHM);

  dwt_rows_kernel<8192, 4098, 2051, 1028, CAP_U><<<NUM_U, 256, U_SHM, stream>>>(
      klist_u, fill_u, item_idx, values, act, u_low, u_high);
  dwt_rows_kernel<16384, 8194, 4099, 2052, CAP_I><<<NUM_I, 256, I_SHM, stream>>>(
      klist_i, fill_i, user_idx, values, pop, i_low, i_high);

  beta_kernel<<<(NUM_U + NUM_I + 255) / 256, 256, 0, stream>>>(
      u_low, u_high, i_low, i_high, out, kAu, kBu, kAi, kBi);
}

// Round 3
// 906.664 us; speedup vs baseline: 2.2111x; 1.6988x over previous
//
#include <hip/hip_runtime.h>
#include <stdint.h>

// ============================================================================
// PopularNicheGraphBuilder: segment-sums -> normalize -> per-row db3 DWT stats
// (in LDS) -> exact replication of jax.random.beta (threefry + Marsaglia-Tsang
// log-space gamma).
//
// Round 3: in-place single-buffer DWT (lo1 overwrites x, lo2 overwrites lo1;
// consumers of position p are at index <= (p+4)/2 < p, so with read-to-regs +
// barrier + write batches this is race-free). LDS 115->69 KB (items, 2
// blocks/CU) and 58->35 KB (users, 4 blocks/CU). Numerics bit-identical to
// round 2 (same per-output tap order, same per-thread accumulation order).
// fill merged into count (one fewer 1M-element pass).
// ============================================================================
#define PARTITIONABLE 1

typedef unsigned long long ull;

#define NUM_U 16384
#define NUM_I 8192
#define CAP_U 160
#define CAP_I 256

// output layout
#define OFF_UPW 0
#define OFF_UMW 16384
#define OFF_IPW 32768
#define OFF_IMW 40960
#define OFF_ACT 49152
#define OFF_POP 65536

// ---------------- threefry2x32 ----------------
struct K2 { uint32_t a, b; };

__host__ __device__ inline void tf2x32(uint32_t k0, uint32_t k1, uint32_t& x0, uint32_t& x1) {
  const uint32_t ks2 = k0 ^ k1 ^ 0x1BD11BDAu;
  x0 += k0; x1 += k1;
#define TF_R(r) { x0 += x1; x1 = (x1 << (r)) | (x1 >> (32 - (r))); x1 ^= x0; }
  TF_R(13) TF_R(15) TF_R(26) TF_R(6)
  x0 += k1; x1 += ks2 + 1u;
  TF_R(17) TF_R(29) TF_R(16) TF_R(24)
  x0 += ks2; x1 += k0 + 2u;
  TF_R(13) TF_R(15) TF_R(26) TF_R(6)
  x0 += k0; x1 += k1 + 3u;
  TF_R(17) TF_R(29) TF_R(16) TF_R(24)
  x0 += k1; x1 += ks2 + 4u;
  TF_R(13) TF_R(15) TF_R(26) TF_R(6)
  x0 += ks2; x1 += k0 + 5u;
#undef TF_R
}

__host__ __device__ inline K2 tf_enc(K2 k, uint32_t x0, uint32_t x1) {
  tf2x32(k.a, k.b, x0, x1);
  K2 r; r.a = x0; r.b = x1; return r;
}

// split(key) -> 2 children
__host__ __device__ inline void split2(K2 k, K2& c0, K2& c1) {
#if PARTITIONABLE
  c0 = tf_enc(k, 0u, 0u);
  c1 = tf_enc(k, 0u, 1u);
#else
  K2 p = tf_enc(k, 0u, 2u);
  K2 q = tf_enc(k, 1u, 3u);
  c0.a = p.a; c0.b = q.a;
  c1.a = p.b; c1.b = q.b;
#endif
}

// split(key, 3)
__device__ inline void split3(K2 k, K2& c0, K2& c1, K2& c2) {
#if PARTITIONABLE
  c0 = tf_enc(k, 0u, 0u);
  c1 = tf_enc(k, 0u, 1u);
  c2 = tf_enc(k, 0u, 2u);
#else
  K2 p = tf_enc(k, 0u, 3u);
  K2 q = tf_enc(k, 1u, 4u);
  K2 r = tf_enc(k, 2u, 5u);
  c0.a = p.a; c0.b = q.a;
  c1.a = r.a; c1.b = p.b;
  c2.a = q.b; c2.b = r.b;
#endif
}

// scalar random_bits(key, 32, ())
__device__ inline uint32_t draw_bits(K2 k) {
  K2 e = tf_enc(k, 0u, 0u);
#if PARTITIONABLE
  return e.a ^ e.b;
#else
  return e.a;
#endif
}

// split(key, B)[i]
__device__ inline K2 elem_key(K2 k, uint32_t i, uint32_t B) {
#if PARTITIONABLE
  return tf_enc(k, 0u, i);
#else
  if (i < (B >> 1)) {
    K2 p = tf_enc(k, 2u * i, B + 2u * i);
    K2 q = tf_enc(k, 2u * i + 1u, B + 2u * i + 1u);
    K2 r; r.a = p.a; r.b = q.a; return r;
  } else {
    uint32_t j = 2u * i - B;
    K2 p = tf_enc(k, j, 2u * i);
    K2 q = tf_enc(k, j + 1u, 2u * i + 1u);
    K2 r; r.a = p.b; r.b = q.b; return r;
  }
#endif
}

__device__ inline float u01_bits(uint32_t b) {
  return __uint_as_float((b >> 9) | 0x3F800000u) - 1.0f;
}

// XLA ErfInv32 (Giles polynomial) -- matches lax.erf_inv on f32
__device__ inline float erfinv_f32(float x) {
  float w = -log1pf(-x * x);
  float p;
  if (w < 5.0f) {
    w = w - 2.5f;
    p = 2.81022636e-08f;
    p = fmaf(p, w, 3.43273939e-07f);
    p = fmaf(p, w, -3.5233877e-06f);
    p = fmaf(p, w, -4.39150654e-06f);
    p = fmaf(p, w, 0.00021858087f);
    p = fmaf(p, w, -0.00125372503f);
    p = fmaf(p, w, -0.00417768164f);
    p = fmaf(p, w, 0.246640727f);
    p = fmaf(p, w, 1.50140941f);
  } else {
    w = sqrtf(w) - 3.0f;
    p = -0.000200214257f;
    p = fmaf(p, w, 0.000100950558f);
    p = fmaf(p, w, 0.00134934322f);
    p = fmaf(p, w, -0.00367342844f);
    p = fmaf(p, w, 0.00573950773f);
    p = fmaf(p, w, -0.0076224613f);
    p = fmaf(p, w, 0.00943887047f);
    p = fmaf(p, w, 1.00167406f);
    p = fmaf(p, w, 2.83297682f);
  }
  return p * x;
}

// jax _gamma_one with log_space=True (Marsaglia-Tsang + boost)
__device__ float log_gamma_sample(K2 key, float alpha_orig) {
  const bool boost = (alpha_orig >= 1.0f);
  const float alpha = boost ? alpha_orig : (alpha_orig + 1.0f);
  const float d = alpha - 0.33333334f;
  const float c = 0.33333334f / sqrtf(d);

  K2 k0, sub;
  split2(key, k0, sub);
  const float u_boost = u01_bits(draw_bits(sub));

  K2 kcur = k0;
  float X = 0.0f, V = 1.0f, U = 2.0f;
  while ((U >= 1.0f - 0.0331f * (X * X)) &&
         (logf(U) >= X * 0.5f + d * ((1.0f - V) + logf(V)))) {
    K2 knext, xk, Uk;
    split3(kcur, knext, xk, Uk);
    kcur = knext;
    float x, v;
    K2 ik = xk;
    do {
      K2 in0, isub;
      split2(ik, in0, isub);
      ik = in0;
      float f = u01_bits(draw_bits(isub));
      // uniform(lo=nextafter(-1,0), hi=1): (hi-lo) rounds to exactly 2.0f
      float u = fmaxf(-0.99999994f, f * 2.0f + (-0.99999994f));
      x = 1.41421356f * erfinv_f32(u);   // sqrt(2) as f32
      v = 1.0f + x * c;
    } while (v <= 0.0f);
    X = x * x;
    V = (v * v) * v;
    U = u01_bits(draw_bits(Uk));
  }
  float lg = logf(d * V);
  if (!boost) lg += log1pf(-u_boost) / alpha_orig;
  return lg;
}

// ---------------- pipeline kernels ----------------

__global__ __launch_bounds__(256) void zero_kernel(ull* p, int n) {
  int i = blockIdx.x * 256 + threadIdx.x;
  if (i < n) p[i] = 0ull;
}

// counts + fixed-point value sums per item, plus CSR-ish fill of both sides
__global__ __launch_bounds__(256) void count_fill_kernel(
    const int* __restrict__ user, const int* __restrict__ item,
    const float* __restrict__ val, int n,
    int* __restrict__ cnt, ull* __restrict__ sv,
    int* __restrict__ fu, int* __restrict__ fi,
    uint32_t* __restrict__ lu, uint32_t* __restrict__ li) {
  for (int k = blockIdx.x * 256 + threadIdx.x; k < n; k += gridDim.x * 256) {
    int it = item[k];
    atomicAdd(&cnt[it], 1);
    atomicAdd(&sv[it], (ull)llrintf(val[k] * 4294967296.0f));  // fixed-point 2^32
    int q = atomicAdd(&fi[it], 1);
    if (q < CAP_I) li[(size_t)it * CAP_I + q] = (uint32_t)k;
    int u = user[k];
    int p = atomicAdd(&fu[u], 1);
    if (p < CAP_U) lu[(size_t)u * CAP_U + p] = (uint32_t)k;
  }
}

__global__ __launch_bounds__(256) void pop_raw_kernel(const int* __restrict__ cnt,
                                                      const ull* __restrict__ sv,
                                                      float* __restrict__ pop,
                                                      double* __restrict__ nrm2) {
  __shared__ float red[4];
  int i = blockIdx.x * 256 + threadIdx.x;
  float p = 0.0f;
  if (i < NUM_I) {
    float svf = (float)((double)sv[i] * (1.0 / 4294967296.0));
    p = svf * log1pf((float)cnt[i]);
    pop[i] = p;
  }
  float sq = p * p;
  for (int o = 32; o > 0; o >>= 1) sq += __shfl_down(sq, o);
  if ((threadIdx.x & 63) == 0) red[threadIdx.x >> 6] = sq;
  __syncthreads();
  if (threadIdx.x == 0) atomicAdd(nrm2, (double)(red[0] + red[1] + red[2] + red[3]));
}

__global__ __launch_bounds__(256) void pop_norm_kernel(float* __restrict__ pop,
                                                       const double* __restrict__ nrm2,
                                                       float* __restrict__ out) {
  int i = blockIdx.x * 256 + threadIdx.x;
  if (i < NUM_I) {
    float nrm = sqrtf((float)(*nrm2));
    float v = pop[i] / (nrm + 1e-8f);
    pop[i] = v;
    out[OFF_POP + i] = v;
  }
}

__global__ __launch_bounds__(256) void act_accum_kernel(const int* __restrict__ user,
                                                        const int* __restrict__ item,
                                                        const float* __restrict__ val, int n,
                                                        const float* __restrict__ pop,
                                                        ull* __restrict__ acc) {
  for (int k = blockIdx.x * 256 + threadIdx.x; k < n; k += gridDim.x * 256) {
    float term = val[k] / log1pf(pop[item[k]] + 1e-8f);
    atomicAdd(&acc[user[k]], (ull)llrintf(term * 16777216.0f));  // fixed-point 2^24
  }
}

__global__ __launch_bounds__(256) void act_pre_kernel(const ull* __restrict__ acc,
                                                      float* __restrict__ act,
                                                      double* __restrict__ nrm2) {
  __shared__ float red[4];
  int u = blockIdx.x * 256 + threadIdx.x;
  float a = 0.0f;
  if (u < NUM_U) {
    a = (float)((double)acc[u] * (1.0 / 16777216.0));
    act[u] = a;
  }
  float sq = a * a;
  for (int o = 32; o > 0; o >>= 1) sq += __shfl_down(sq, o);
  if ((threadIdx.x & 63) == 0) red[threadIdx.x >> 6] = sq;
  __syncthreads();
  if (threadIdx.x == 0) atomicAdd(nrm2, (double)(red[0] + red[1] + red[2] + red[3]));
}

__global__ __launch_bounds__(256) void act_norm_kernel(float* __restrict__ act,
                                                       const double* __restrict__ nrm2,
                                                       float* __restrict__ out) {
  int u = blockIdx.x * 256 + threadIdx.x;
  if (u < NUM_U) {
    float nrm = sqrtf((float)(*nrm2));
    float v = act[u] / (nrm + 1e-8f);
    act[u] = v;
    out[OFF_ACT + u] = v;
  }
}

// One in-place DWT analysis level over a padded LDS buffer.
// Data element i lives at buf[4+i]; front pad 4 is always zero. Input occupies
// data [0..NIN-1]; output lo overwrites data [0..MOUT-1]. Safe because every
// consumer of data position p is an output index <= (p+4)/2 < p; each batch
// reads its 24 inputs to registers, barriers, then writes. Cross-batch
// read/write regions are disjoint (reads of batch b start at 2048b-4 >
// 1024(b-1)+1023). Per-output tap order and per-thread accumulation order are
// identical to round 2 (numerics preserved).
template <int MOUT, bool LAST>
__device__ inline void dwt_level_inplace(float* __restrict__ buf, int tid,
                                         float& h_acc, float& lo_acc) {
  for (int base = 0; base < MOUT; base += 1024) {
    int m0 = base + tid;
    float lov[4], hiv[4];
    int mv[4]; bool okv[4];
#pragma unroll
    for (int u = 0; u < 4; ++u) {
      int m = m0 + (u << 8);
      bool ok = m < MOUT;
      mv[u] = m; okv[u] = ok;
      int mm = ok ? m : (MOUT - 1);
      const float* s = buf + 2 * mm + 5;   // s[-t] == data[2*mm+1-t]
      float x0 = s[0], x1 = s[-1], x2 = s[-2], x3 = s[-3], x4 = s[-4], x5 = s[-5];
      float lo = 0.0f, hi = 0.0f;
      lo += 0.035226291882100656f * x0;  hi += -0.3326705529509569f * x0;
      lo += -0.08544127388224149f * x1;  hi += 0.8068915093133388f * x1;
      lo += -0.13501102001039084f * x2;  hi += -0.4598775021193313f * x2;
      lo += 0.4598775021193313f * x3;    hi += -0.13501102001039084f * x3;
      lo += 0.8068915093133388f * x4;    hi += 0.08544127388224149f * x4;
      lo += 0.3326705529509569f * x5;    hi += 0.035226291882100656f * x5;
      lov[u] = lo; hiv[u] = hi;
    }
    if (!LAST) __syncthreads();
#pragma unroll
    for (int u = 0; u < 4; ++u) {
      if (okv[u]) {
        if (!LAST) buf[4 + mv[u]] = lov[u];
        else lo_acc += lov[u];
        h_acc += hiv[u] * hiv[u];
      }
    }
  }
}

// per-row 3-level db3 DWT stats, dense row built in LDS, last-write-wins dedup
template <int N, int M1, int M2, int M3, int CAP>
__global__ __launch_bounds__(256) void dwt_rows_kernel(
    const uint32_t* __restrict__ klist, const int* __restrict__ rowlen,
    const int* __restrict__ colsrc, const float* __restrict__ values,
    const float* __restrict__ scale_vec,
    float* __restrict__ low_out, float* __restrict__ high_out) {
  extern __shared__ float smem[];
  float* xb = smem;                        // N + 12 (data at +4)
  float* ev = xb + (N + 12);               // CAP
  int* ecol = (int*)(ev + CAP);            // CAP
  int* ek = (int*)(ecol + CAP);            // CAP
  float* red = (float*)(ek + CAP);         // 16

  const int r = blockIdx.x;
  const int tid = threadIdx.x;
  const float scale = 1.0f + scale_vec[r];
  int n = rowlen[r];
  if (n > CAP) n = CAP;

  for (int i = tid; i < N + 12; i += 256) xb[i] = 0.0f;
  for (int e = tid; e < n; e += 256) {
    uint32_t k = klist[(size_t)r * CAP + e];
    ecol[e] = colsrc[k];
    ek[e] = (int)k;
    ev[e] = values[k] * scale;
  }
  __syncthreads();
  // duplicate resolution: entry with max original index wins (XLA CPU scatter)
  for (int e = tid; e < n; e += 256) {
    int cme = ecol[e], kme = ek[e];
    bool win = true;
    for (int j = 0; j < n; ++j)
      if (ecol[j] == cme && ek[j] > kme) { win = false; break; }
    if (win) xb[4 + cme] = ev[e];
  }
  __syncthreads();

  float h1 = 0.0f, h2 = 0.0f, h3 = 0.0f, slo = 0.0f;
  float dummy = 0.0f;
  dwt_level_inplace<M1, false>(xb, tid, h1, dummy);
  __syncthreads();
  // zero the stale-x gap read by the next level (data [M1 .. M1+7])
  if (tid < 8) xb[4 + M1 + tid] = 0.0f;
  __syncthreads();
  dwt_level_inplace<M2, false>(xb, tid, h2, dummy);
  __syncthreads();
  if (tid < 8) xb[4 + M2 + tid] = 0.0f;
  __syncthreads();
  dwt_level_inplace<M3, true>(xb, tid, h3, slo);

  for (int o = 32; o > 0; o >>= 1) {
    h1 += __shfl_down(h1, o);
    h2 += __shfl_down(h2, o);
    h3 += __shfl_down(h3, o);
    slo += __shfl_down(slo, o);
  }
  int w = tid >> 6, lane = tid & 63;
  if (lane == 0) { red[w] = h1; red[4 + w] = h2; red[8 + w] = h3; red[12 + w] = slo; }
  __syncthreads();
  if (tid == 0) {
    float s1 = red[0] + red[1] + red[2] + red[3];
    float s2 = red[4] + red[5] + red[6] + red[7];
    float s3 = red[8] + red[9] + red[10] + red[11];
    float sl = red[12] + red[13] + red[14] + red[15];
    low_out[r] = sl / (float)M3;
    high_out[r] = sqrtf(s1) + sqrtf(s2) + sqrtf(s3);
  }
}

__global__ __launch_bounds__(256) void beta_kernel(
    const float* __restrict__ u_low, const float* __restrict__ u_high,
    const float* __restrict__ i_low, const float* __restrict__ i_high,
    float* __restrict__ out, K2 kAu, K2 kBu, K2 kAi, K2 kBi) {
  int t = blockIdx.x * 256 + threadIdx.x;
  if (t >= NUM_U + NUM_I) return;
  float low, high;
  K2 ka, kb;
  int o0, o1;
  if (t < NUM_U) {
    low = u_low[t]; high = u_high[t];
    ka = elem_key(kAu, (uint32_t)t, (uint32_t)NUM_U);
    kb = elem_key(kBu, (uint32_t)t, (uint32_t)NUM_U);
    o0 = OFF_UPW + t; o1 = OFF_UMW + t;
  } else {
    int j = t - NUM_U;
    low = i_low[j]; high = i_high[j];
    ka = elem_key(kAi, (uint32_t)j, (uint32_t)NUM_I);
    kb = elem_key(kBi, (uint32_t)j, (uint32_t)NUM_I);
    o0 = OFF_IPW + j; o1 = OFF_IMW + j;
  }
  float a1 = fmaxf(low, 1e-6f);
  float a2 = fmaxf(high, 1e-6f);
  float s = a1 + a2;
  a1 = a1 / s;
  a2 = a2 / s;
  float lga = log_gamma_sample(ka, 10.0f * a1);
  float lgb = log_gamma_sample(kb, 10.0f * a2);
  float m = fmaxf(lga, lgb);
  float na = expf(lga - m);
  float nb = expf(lgb - m);
  float w = na / (na + nb);
  out[o0] = w;
  out[o1] = 1.0f - w;
}

// ---------------- host ----------------
extern "C" void kernel_launch(void* const* d_in, const int* in_sizes, int n_in,
                              void* d_out, int out_size, void* d_ws, size_t ws_size,
                              hipStream_t stream) {
  const int* user_idx = (const int*)d_in[0];
  const int* item_idx = (const int*)d_in[1];
  const float* values = (const float*)d_in[2];
  const int NNZ = in_sizes[0];

  char* ws = (char*)d_ws;
  double* nrm2_pop = (double*)(ws + 0);
  double* nrm2_act = (double*)(ws + 8);
  ull* sv_acc = (ull*)(ws + 16);
  ull* act_acc = (ull*)(ws + 65552);
  int* cnt_i = (int*)(ws + 196624);
  float* pop = (float*)(ws + 229392);
  float* act = (float*)(ws + 262160);
  int* fill_u = (int*)(ws + 327696);
  int* fill_i = (int*)(ws + 393232);
  float* u_low = (float*)(ws + 426000);
  float* u_high = (float*)(ws + 491536);
  float* i_low = (float*)(ws + 557072);
  float* i_high = (float*)(ws + 589840);
  uint32_t* klist_u = (uint32_t*)(ws + 622608);
  uint32_t* klist_i = (uint32_t*)(ws + 11108368);
  float* out = (float*)d_out;

  // host-side key derivation: root=key(42)=(0,42); ku,ki=split(root); then
  // (key_a,key_b)=split(k) inside beta for each side.
  K2 root; root.a = 0u; root.b = 42u;
  K2 ku, ki, kAu, kBu, kAi, kBi;
  split2(root, ku, ki);
  split2(ku, kAu, kBu);
  split2(ki, kAi, kBi);

  const int zero_words = 622608 / 8;
  zero_kernel<<<(zero_words + 255) / 256, 256, 0, stream>>>((ull*)ws, zero_words);
  count_fill_kernel<<<1024, 256, 0, stream>>>(user_idx, item_idx, values, NNZ,
                                              cnt_i, sv_acc, fill_u, fill_i, klist_u, klist_i);
  pop_raw_kernel<<<NUM_I / 256, 256, 0, stream>>>(cnt_i, sv_acc, pop, nrm2_pop);
  pop_norm_kernel<<<NUM_I / 256, 256, 0, stream>>>(pop, nrm2_pop, out);
  act_accum_kernel<<<1024, 256, 0, stream>>>(user_idx, item_idx, values, NNZ, pop, act_acc);
  act_pre_kernel<<<NUM_U / 256, 256, 0, stream>>>(act_acc, act, nrm2_act);
  act_norm_kernel<<<NUM_U / 256, 256, 0, stream>>>(act, nrm2_act, out);

  // user rows: N=8192, M1=4098, M2=2051, M3=1028 -> ~34.8 KB, 4 blocks/CU
  constexpr int U_SHM = ((8192 + 12) + 3 * CAP_U + 16) * 4;
  // item rows: N=16384, M1=8194, M2=4099, M3=2052 -> ~68.7 KB, 2 blocks/CU
  constexpr int I_SHM = ((16384 + 12) + 3 * CAP_I + 16) * 4;
  hipFuncSetAttribute((const void*)dwt_rows_kernel<8192, 4098, 2051, 1028, CAP_U>,
                      hipFuncAttributeMaxDynamicSharedMemorySize, U_SHM);
  hipFuncSetAttribute((const void*)dwt_rows_kernel<16384, 8194, 4099, 2052, CAP_I>,
                      hipFuncAttributeMaxDynamicSharedMemorySize, I_SHM);

  dwt_rows_kernel<8192, 4098, 2051, 1028, CAP_U><<<NUM_U, 256, U_SHM, stream>>>(
      klist_u, fill_u, item_idx, values, act, u_low, u_high);
  dwt_rows_kernel<16384, 8194, 4099, 2052, CAP_I><<<NUM_I, 256, I_SHM, stream>>>(
      klist_i, fill_i, user_idx, values, pop, i_low, i_high);

  beta_kernel<<<(NUM_U + NUM_I + 255) / 256, 256, 0, stream>>>(
      u_low, u_high, i_low, i_high, out, kAu, kBu, kAi, kBi);
}